// Round 3
// baseline (396.393 us; speedup 1.0000x reference)
//
#include <hip/hip_runtime.h>
#include <hip/hip_bf16.h>

#define DM 512
#define BCN 2048
#define XPATCH ((size_t)BCN * 64 * DM)     // 67,108,864 floats

typedef float f32x4 __attribute__((ext_vector_type(4)));

__device__ __forceinline__ unsigned pack_bf16(float a, float b) {
    __hip_bfloat162 h = __float22bfloat162_rn(make_float2(a, b));
    return *reinterpret_cast<unsigned*>(&h);
}
__device__ __forceinline__ float2 unpack_bf16(unsigned p) {
    float2 r;
    r.x = __uint_as_float(p << 16);
    r.y = __uint_as_float(p & 0xffff0000u);
    return r;
}
__device__ __forceinline__ void fma4p(f32x4& a, float xv, float2 wa, float2 wb) {
    a.x = fmaf(xv, wa.x, a.x);
    a.y = fmaf(xv, wa.y, a.y);
    a.z = fmaf(xv, wb.x, a.z);
    a.w = fmaf(xv, wb.y, a.w);
}
__device__ __forceinline__ void fma4f(f32x4& a, float xv, f32x4 w) {
    a.x = fmaf(xv, w.x, a.x);
    a.y = fmaf(xv, w.y, a.y);
    a.z = fmaf(xv, w.z, a.z);
    a.w = fmaf(xv, w.w, a.w);
}

// 64-lane sum via DPP (VALU pipe, zero DS-pipe traffic), result uniform.
// Canonical GCN sequence: row_shr 1/2/4/8 then row_bcast 15/31; total in lane 63.
template<int CTRL>
__device__ __forceinline__ float dpp_add(float x) {
    int mv = __builtin_amdgcn_update_dpp(0, __float_as_int(x), CTRL, 0xf, 0xf, false);
    return x + __int_as_float(mv);
}
__device__ __forceinline__ float wave_sum(float x) {
    x = dpp_add<0x111>(x);   // row_shr:1
    x = dpp_add<0x112>(x);   // row_shr:2
    x = dpp_add<0x114>(x);   // row_shr:4
    x = dpp_add<0x118>(x);   // row_shr:8
    x = dpp_add<0x142>(x);   // row_bcast:15
    x = dpp_add<0x143>(x);   // row_bcast:31
    return __int_as_float(__builtin_amdgcn_readlane(__float_as_int(x), 63));
}

// Grid: 2048 blocks x 256 threads, one block per bc row (R0 structure).
// DS-pipe relief: x is read via wave-uniform GLOBAL loads (scalarizes to
// s_load through the scalar cache) in BOTH phases -> xs[] LDS deleted.
// Shfl butterflies -> DPP adds (VALU). Gumbel -> uniform loads.
// Only remaining DS users: w32 staging writes + e==2 dot reads.
// w8/w16: global fp32 (VMEM/L2 path, R0's best measured config; fp32 absmax).
// Stores: regular (NT measured -80us in R1). Block swizzle: each XCD gets a
// contiguous 256-bc span -> 8 contiguous 32MB write windows instead of 2048
// interleaved 128KB streams (DRAM row locality for the 268MB store stream).
__global__ __launch_bounds__(256, 4) void ape_fused(
    const float* __restrict__ x,
    const float* __restrict__ gumbel,
    const float* __restrict__ w1,
    const float* __restrict__ b1,
    const float* __restrict__ w2,
    const float* __restrict__ b2,
    const float* __restrict__ w8,
    const float* __restrict__ w16,
    const float* __restrict__ w32,
    float* __restrict__ out)
{
    __shared__ unsigned w32s[32 * 256];    // 32 KB: 32 rows x 128 uint2 (bf16 pairs)

    const int bid = blockIdx.x;
    const int tid = threadIdx.x;
    const int bc  = ((bid & 7) << 8) | (bid >> 3);   // XCD-contiguous, bijective

    const float* __restrict__ xrow = x + (size_t)bc * DM;

    // ---- stage w32 -> LDS bf16 (all threads, 16 float4 each) ----
    #pragma unroll
    for (int it = 0; it < 16; ++it) {
        int f4   = it * 256 + tid;         // 0..4095
        int row  = f4 >> 7;
        int col4 = f4 & 127;
        f32x4 v = reinterpret_cast<const f32x4*>(w32 + (size_t)row * DM)[col4];
        reinterpret_cast<uint2*>(w32s)[row * 128 + col4] =
            make_uint2(pack_bf16(v.x, v.y), pack_bf16(v.z, v.w));
    }

    const int lane = tid & 63;
    const int wv   = tid >> 6;
    const int pw   = wv >> 1;              // region parity this wave consumes

    // ---- Phase A: classifier, zero LDS (overlaps w32 staging latency) ----
    unsigned epack = 0;                    // 2 bits per owned region slot
    {
        float w1r[32];
        #pragma unroll
        for (int q = 0; q < 32; ++q) w1r[q] = w1[q * 64 + lane];
        const float w2r0 = w2[lane * 3 + 0];
        const float w2r1 = w2[lane * 3 + 1];
        const float w2r2 = w2[lane * 3 + 2];
        const float b1r  = b1[lane];
        const float b20  = b2[0], b21 = b2[1], b22 = b2[2];

        #pragma unroll
        for (int p = 0; p < 8; ++p) {
            const int rr = p * 2 + pw;
            const float* xr = xrow + rr * 32;          // uniform -> s_load
            float a = b1r;
            #pragma unroll
            for (int q = 0; q < 32; ++q) a = fmaf(xr[q], w1r[q], a);
            float h = fmaxf(a, 0.f);
            float s0 = wave_sum(h * w2r0);             // DPP, uniform result
            float s1 = wave_sum(h * w2r1);
            float s2 = wave_sum(h * w2r2);
            const float* g = gumbel + ((size_t)bc * 16 + rr) * 3;  // uniform
            s0 += b20 + g[0];
            s1 += b21 + g[1];
            s2 += b22 + g[2];
            int best = 0; float bs = s0;
            if (s1 > bs) { bs = s1; best = 1; }
            if (s2 > bs) { best = 2; }
            epack |= (unsigned)best << (2 * p);
            if (((wv & 1) | lane) == 0)    // wave 0 writes even rr, wave 2 odd
                out[XPATCH + (size_t)rr * BCN + bc] = (float)best;
        }
        epack = (unsigned)__builtin_amdgcn_readfirstlane((int)epack);
    }
    __syncthreads();                       // w32 staging visible; only barrier

    // ---- Phase B: expert embedding + PE ----
    const int rp = tid >> 7;               // == pw (wave-uniform)
    const int cg = tid & 127;              // float4 column group
    const int c0 = cg * 4;
    const float kln = -9.210340371976184f / 256.0f;   // -ln(10000)/256
    const float dv0 = __expf((float)(cg * 2)     * kln);
    const float dv1 = __expf((float)(cg * 2 + 1) * kln);
    const uint2*  w32b = reinterpret_cast<const uint2*>(w32s) + cg;
    const f32x4*  w8b  = reinterpret_cast<const f32x4*>(w8)  + cg;
    const f32x4*  w16b = reinterpret_cast<const f32x4*>(w16) + cg;

    #pragma unroll 1
    for (int p = 0; p < 8; ++p) {
        const int rr = p * 2 + rp;
        const int e  = (int)((epack >> (2 * p)) & 3u);   // scalar branch
        const float* xr = xrow + rr * 32;                // uniform -> s_load
        f32x4 a0 = {0,0,0,0}, a1 = {0,0,0,0}, a2 = {0,0,0,0}, a3 = {0,0,0,0};

        if (e == 0) {                       // p=8: 4 distinct dots of len 8
            #pragma unroll
            for (int q = 0; q < 8; ++q) {
                f32x4 wvv = w8b[q * 128];
                fma4f(a0, xr[q],      wvv);
                fma4f(a1, xr[8  + q], wvv);
                fma4f(a2, xr[16 + q], wvv);
                fma4f(a3, xr[24 + q], wvv);
            }
        } else if (e == 1) {                // p=16: rows 0..2 patch0, row 3 patch1
            #pragma unroll
            for (int q = 0; q < 16; ++q) {
                f32x4 wvv = w16b[q * 128];
                fma4f(a0, xr[q],      wvv);
                fma4f(a3, xr[16 + q], wvv);
            }
            a1 = a0; a2 = a0;
        } else {                            // p=32: 1 dot of len 32 (LDS bf16)
            #pragma unroll
            for (int q = 0; q < 32; ++q) {
                uint2 pk = w32b[q * 128];
                float2 wa = unpack_bf16(pk.x), wb = unpack_bf16(pk.y);
                fma4p(a0, xr[q], wa, wb);
            }
            a1 = a0; a2 = a0; a3 = a0;
        }

        const size_t ob = ((size_t)(bc * 64 + rr * 4)) * DM + c0;
        f32x4 av[4] = {a0, a1, a2, a3};
        #pragma unroll
        for (int t = 0; t < 4; ++t) {
            float sv0, cv0, sv1, cv1;
            const float pos = (float)(rr * 4 + t);
            __sincosf(pos * dv0, &sv0, &cv0);
            __sincosf(pos * dv1, &sv1, &cv1);
            f32x4 o;
            o.x = av[t].x + sv0;
            o.y = av[t].y + cv0;
            o.z = av[t].z + sv1;
            o.w = av[t].w + cv1;
            *reinterpret_cast<f32x4*>(out + ob + (size_t)t * DM) = o;
        }
    }
}

extern "C" void kernel_launch(void* const* d_in, const int* in_sizes, int n_in,
                              void* d_out, int out_size, void* d_ws, size_t ws_size,
                              hipStream_t stream) {
    const float* x      = (const float*)d_in[0];
    const float* gumbel = (const float*)d_in[1];
    const float* w1     = (const float*)d_in[2];
    const float* b1     = (const float*)d_in[3];
    const float* w2     = (const float*)d_in[4];
    const float* b2     = (const float*)d_in[5];
    const float* w8     = (const float*)d_in[6];
    const float* w16    = (const float*)d_in[7];
    const float* w32    = (const float*)d_in[8];
    float* out = (float*)d_out;

    ape_fused<<<BCN, 256, 0, stream>>>(x, gumbel, w1, b1, w2, b2, w8, w16, w32, out);
}

// Round 5
// 321.188 us; speedup vs baseline: 1.2341x; 1.2341x over previous
//
#include <hip/hip_runtime.h>

#define DM 512
#define BCN 2048
#define XPATCH ((size_t)BCN * 64 * DM)     // 67,108,864 floats

typedef float f32x8 __attribute__((ext_vector_type(8)));

// Launder a wave-uniform pointer into SGPRs (readfirstlane lo/hi) so the
// inline-asm "s" constraint can allocate an SGPR pair. Values derived from
// threadIdx (even wave-uniformly) are "divergent" to the compiler otherwise.
__device__ __forceinline__ const float* uniform_ptr(const float* p) {
    unsigned long long v = (unsigned long long)p;
    unsigned lo = __builtin_amdgcn_readfirstlane((unsigned)v);
    unsigned hi = __builtin_amdgcn_readfirstlane((unsigned)(v >> 32));
    return (const float*)(((unsigned long long)hi << 32) | lo);
}

// Forced-scalar load of 32 consecutive floats (wave-uniform address) into SGPRs.
// SMEM path -> lgkmcnt only: completely decoupled from the store stream's vmcnt.
__device__ __forceinline__ void sload32(const float* p, f32x8& a, f32x8& b,
                                        f32x8& c, f32x8& d) {
    asm volatile(
        "s_load_dwordx8 %0, %4, 0x0\n\t"
        "s_load_dwordx8 %1, %4, 0x20\n\t"
        "s_load_dwordx8 %2, %4, 0x40\n\t"
        "s_load_dwordx8 %3, %4, 0x60\n\t"
        "s_waitcnt lgkmcnt(0)"
        : "=&s"(a), "=&s"(b), "=&s"(c), "=&s"(d)
        : "s"(uniform_ptr(p)));
}
// Forced-scalar load of 3 floats (gumbel triple).
__device__ __forceinline__ void sload3(const float* p, float& a, float& b, float& c) {
    asm volatile(
        "s_load_dword %0, %3, 0x0\n\t"
        "s_load_dword %1, %3, 0x4\n\t"
        "s_load_dword %2, %3, 0x8\n\t"
        "s_waitcnt lgkmcnt(0)"
        : "=&s"(a), "=&s"(b), "=&s"(c)
        : "s"(uniform_ptr(p)));
}

// 64-lane sum via DPP (VALU pipe), uniform result (verified passing in R3).
template<int CTRL>
__device__ __forceinline__ float dpp_add(float x) {
    int mv = __builtin_amdgcn_update_dpp(0, __float_as_int(x), CTRL, 0xf, 0xf, false);
    return x + __int_as_float(mv);
}
__device__ __forceinline__ float wave_sum(float x) {
    x = dpp_add<0x111>(x);   // row_shr:1
    x = dpp_add<0x112>(x);   // row_shr:2
    x = dpp_add<0x114>(x);   // row_shr:4
    x = dpp_add<0x118>(x);   // row_shr:8
    x = dpp_add<0x142>(x);   // row_bcast:15
    x = dpp_add<0x143>(x);   // row_bcast:31
    return __int_as_float(__builtin_amdgcn_readlane(__float_as_int(x), 63));
}

// Grid: 512 blocks x 512 threads, ALL-RESIDENT (2 blocks/CU, 16 waves/CU).
// Thread owns ONE output column (col = tid): expert weights live in 56 VGPRs,
// loaded once at t=0 by every block simultaneously (perfect L2 temporal
// locality BEFORE the store stream takes over). Each block processes 4 bc
// rows sequentially. x + gumbel come in via forced s_load (SMEM/lgkmcnt).
// Phase B's only vector-memory ops are stores -> never waited on.
// LDS: eidx[2][16] (double-buffered -> ONE barrier per bc).
__global__ __launch_bounds__(512, 4) void ape_fused(
    const float* __restrict__ x,
    const float* __restrict__ gumbel,
    const float* __restrict__ w1,
    const float* __restrict__ b1,
    const float* __restrict__ w2,
    const float* __restrict__ b2,
    const float* __restrict__ w8,
    const float* __restrict__ w16,
    const float* __restrict__ w32,
    float* __restrict__ out)
{
    __shared__ int eidx[2][16];

    const int tid  = threadIdx.x;
    const int lane = tid & 63;
    const int wv   = tid >> 6;             // wave 0..7
    const int col  = tid;                  // owned output column 0..511

    // ---- per-thread weight registers (col-specific), coalesced loads ----
    float w8r[8], w16r[16], w32r[32], w1r[32];
    #pragma unroll
    for (int q = 0; q < 8;  ++q) w8r[q]  = w8 [(size_t)q * DM + col];
    #pragma unroll
    for (int q = 0; q < 16; ++q) w16r[q] = w16[(size_t)q * DM + col];
    #pragma unroll
    for (int q = 0; q < 32; ++q) w32r[q] = w32[(size_t)q * DM + col];
    #pragma unroll
    for (int q = 0; q < 32; ++q) w1r[q]  = w1[q * 64 + lane];
    const float b1r  = b1[lane];
    const float w2r0 = w2[lane * 3 + 0];
    const float w2r1 = w2[lane * 3 + 1];
    const float w2r2 = w2[lane * 3 + 2];
    const float b20  = b2[0], b21 = b2[1], b22 = b2[2];

    // ---- PE per-column constants: pe[pos,col] = sin(pos*dv + (col&1)*pi/2) ----
    const float kln = -9.210340371976184f / 256.0f;   // -ln(10000)/256
    const float dv  = __expf(kln * (float)(col >> 1));
    const float ph  = (col & 1) ? 1.5707963267948966f : 0.0f;

    #pragma unroll 1
    for (int i = 0; i < 4; ++i) {
        const int bc = blockIdx.x * 4 + i;
        const float* __restrict__ xrow = x + (size_t)bc * DM;
        int* ei = eidx[i & 1];             // double buffer: 1 barrier per bc

        // ---- Phase A: classifier; wave wv owns regions 2wv, 2wv+1 ----
        #pragma unroll
        for (int s = 0; s < 2; ++s) {
            const int rr = wv * 2 + s;
            f32x8 xa, xb, xc, xd;
            sload32(xrow + rr * 32, xa, xb, xc, xd);
            float a = b1r;
            #pragma unroll
            for (int q = 0; q < 8; ++q) {
                a = fmaf(xa[q], w1r[q],      a);
                a = fmaf(xb[q], w1r[8 + q],  a);
                a = fmaf(xc[q], w1r[16 + q], a);
                a = fmaf(xd[q], w1r[24 + q], a);
            }
            const float h = fmaxf(a, 0.f);
            float s0 = wave_sum(h * w2r0);
            float s1 = wave_sum(h * w2r1);
            float s2 = wave_sum(h * w2r2);
            float g0, g1, g2;
            sload3(gumbel + ((size_t)bc * 16 + rr) * 3, g0, g1, g2);
            s0 += b20 + g0; s1 += b21 + g1; s2 += b22 + g2;
            int best = 0; float bs = s0;
            if (s1 > bs) { bs = s1; best = 1; }
            if (s2 > bs) best = 2;
            if (lane == 0) {
                ei[rr] = best;
                out[XPATCH + (size_t)rr * BCN + bc] = (float)best;
            }
        }
        __syncthreads();                   // eidx visible; only barrier per bc

        // ---- Phase B: embedding + PE; zero vector loads, stores unwaited ----
        #pragma unroll 1
        for (int rr = 0; rr < 16; ++rr) {
            const int e = __builtin_amdgcn_readfirstlane(ei[rr]);
            f32x8 xa, xb, xc, xd;
            sload32(xrow + rr * 32, xa, xb, xc, xd);
            float a0, a1, a2, a3;
            if (e == 0) {                  // p=8: 4 distinct dots of len 8
                a0 = a1 = a2 = a3 = 0.f;
                #pragma unroll
                for (int q = 0; q < 8; ++q) {
                    a0 = fmaf(xa[q], w8r[q], a0);
                    a1 = fmaf(xb[q], w8r[q], a1);
                    a2 = fmaf(xc[q], w8r[q], a2);
                    a3 = fmaf(xd[q], w8r[q], a3);
                }
            } else if (e == 1) {           // p=16: rows 0..2 patch0, row 3 patch1
                float d0 = 0.f, d1 = 0.f;
                #pragma unroll
                for (int q = 0; q < 8; ++q) {
                    d0 = fmaf(xa[q], w16r[q],     d0);
                    d0 = fmaf(xb[q], w16r[8 + q], d0);
                    d1 = fmaf(xc[q], w16r[q],     d1);
                    d1 = fmaf(xd[q], w16r[8 + q], d1);
                }
                a0 = a1 = a2 = d0; a3 = d1;
            } else {                       // p=32: 1 dot of len 32
                float d = 0.f;
                #pragma unroll
                for (int q = 0; q < 8; ++q) {
                    d = fmaf(xa[q], w32r[q],      d);
                    d = fmaf(xb[q], w32r[8 + q],  d);
                    d = fmaf(xc[q], w32r[16 + q], d);
                    d = fmaf(xd[q], w32r[24 + q], d);
                }
                a0 = a1 = a2 = a3 = d;
            }

            const size_t ob   = ((size_t)(bc * 64 + rr * 4)) * DM + col;
            const float  base = (float)(rr * 4) * dv + ph;
            out[ob]          = a0 + __sinf(base);
            out[ob +     DM] = a1 + __sinf(base + dv);
            out[ob + 2 * DM] = a2 + __sinf(base + 2.f * dv);
            out[ob + 3 * DM] = a3 + __sinf(base + 3.f * dv);
        }
    }
}

extern "C" void kernel_launch(void* const* d_in, const int* in_sizes, int n_in,
                              void* d_out, int out_size, void* d_ws, size_t ws_size,
                              hipStream_t stream) {
    const float* x      = (const float*)d_in[0];
    const float* gumbel = (const float*)d_in[1];
    const float* w1     = (const float*)d_in[2];
    const float* b1     = (const float*)d_in[3];
    const float* w2     = (const float*)d_in[4];
    const float* b2     = (const float*)d_in[5];
    const float* w8     = (const float*)d_in[6];
    const float* w16    = (const float*)d_in[7];
    const float* w32    = (const float*)d_in[8];
    float* out = (float*)d_out;

    ape_fused<<<512, 512, 0, stream>>>(x, gumbel, w1, b1, w2, b2, w8, w16, w32, out);
}